// Round 6
// baseline (117.108 us; speedup 1.0000x reference)
//
#include <hip/hip_runtime.h>
#include <math.h>

#define HH 256
#define WW 256
#define NG 714
#define NROWS 768          // padded to 3x256 prep grid; pad rows always culled
#define NGP4 716           // s_tz padded for float4 rank loop
#define FOCALF 128.0f
#define EPS2D_F 0.3f
#define ALPHA_MIN_F (1.0f/255.0f)
#define CAM_T_F 8.0f
#define LOG2E_F 1.4426950408889634f
#define PR 12              // floats/row: [mx,my,A2n,B2n][C2n,K,cr,cg][cb,e,f,thr]
#define NTILES 256         // 8 x-tiles (32 px) x 32 y-tiles (8 px)
#define MAXL NROWS         // per-tile list capacity (rows)
#define NPX 65536

// Kernel 1: projection + conic + stable depth rank + scatter into sorted rows.
// Conic stored NEGATED, prefolded with log2(e); K = log2(op) folded additively:
// sg = A2n*dx^2 + B2n*dx*dy + C2n*dy^2 + K  ->  alpha = exp2(sg) = op*exp(-sigma).
// Cull fields: e = C-B^2/4A, f = A-B^2/4C (positive conic, >=0);
// gaussian is irrelevant for a box iff max(e*dymin^2, f*dxmin^2) > thr = log2(255)+K
// (then alpha < 1/255 for EVERY pixel in the box -> reference zeroes it: cull is EXACT).
__global__ __launch_bounds__(256) void gs_prep(
    const float* __restrict__ means, const float* __restrict__ quats,
    const float* __restrict__ scales, const float* __restrict__ opacities,
    const float* __restrict__ rgbs, float* __restrict__ params)
{
    __shared__ float s_tz[NGP4];
    const int lane = threadIdx.x;
    const int i = blockIdx.x * 256 + lane;

    for (int j = lane; j < NGP4; j += 256)
        s_tz[j] = (j < NG) ? (means[3*j+2] + CAM_T_F) : INFINITY;
    __syncthreads();

    if (i >= NROWS) return;
    if (i >= NG) {                      // pad rows: always culled (0 > thr=-1)
        float4* row = (float4*)(params + i*PR);
        row[0] = make_float4(0.f,0.f,0.f,0.f);
        row[1] = make_float4(0.f,0.f,0.f,0.f);
        row[2] = make_float4(0.f,0.f,0.f,-1.f);
        return;
    }

    float m0 = means[i*3+0], m1 = means[i*3+1];
    float tz = s_tz[i];
    float qw = quats[i*4+0], qx = quats[i*4+1], qy = quats[i*4+2], qz = quats[i*4+3];
    float qn = rsqrtf(qw*qw + qx*qx + qy*qy + qz*qz);
    qw*=qn; qx*=qn; qy*=qn; qz*=qn;
    float sx = scales[i*3+0], sy = scales[i*3+1], sz = scales[i*3+2];
    float s0 = sx*sx, s1 = sy*sy, s2 = sz*sz;
    float R00 = 1.f-2.f*(qy*qy+qz*qz), R01 = 2.f*(qx*qy-qw*qz), R02 = 2.f*(qx*qz+qw*qy);
    float R10 = 2.f*(qx*qy+qw*qz),     R11 = 1.f-2.f*(qx*qx+qz*qz), R12 = 2.f*(qy*qz-qw*qx);
    float R20 = 2.f*(qx*qz-qw*qy),     R21 = 2.f*(qy*qz+qw*qx),     R22 = 1.f-2.f*(qx*qx+qy*qy);
    float S00 = R00*R00*s0 + R01*R01*s1 + R02*R02*s2;
    float S01 = R00*R10*s0 + R01*R11*s1 + R02*R12*s2;
    float S02 = R00*R20*s0 + R01*R21*s1 + R02*R22*s2;
    float S11 = R10*R10*s0 + R11*R11*s1 + R12*R12*s2;
    float S12 = R10*R20*s0 + R11*R21*s1 + R12*R22*s2;
    float S22 = R20*R20*s0 + R21*R21*s1 + R22*R22*s2;
    float inv = 1.f/tz;
    float mx = FOCALF*m0*inv + 0.5f*WW;
    float my = FOCALF*m1*inv + 0.5f*HH;
    float j0 = FOCALF*inv;
    float j2 = -FOCALF*m0*inv*inv;
    float j5 = -FOCALF*m1*inv*inv;
    float a = j0*j0*S00 + 2.f*j0*j2*S02 + j2*j2*S22 + EPS2D_F;
    float b = j0*(j0*S01 + j2*S12) + j5*(j0*S02 + j2*S22);
    float c = j0*j0*S11 + 2.f*j0*j5*S12 + j5*j5*S22 + EPS2D_F;
    float det = a*c - b*b;
    float idet = 1.f/det;
    float hA = 0.5f*c*idet*LOG2E_F;      // positive conic terms (log2-scaled)
    float Bc = -b*idet*LOG2E_F;
    float hC = 0.5f*a*idet*LOG2E_F;
    float e  = hC - Bc*Bc/(4.f*hA);      // min over dx of sigma' = e*dy^2
    float f  = hA - Bc*Bc/(4.f*hC);      // min over dy of sigma' = f*dx^2
    float op = 1.f/(1.f+__expf(-opacities[i]));
    float K  = log2f(op);                // folded into exponent
    float thr = log2f(255.f) + K;        // cull iff bound > thr
    float cr = 1.f/(1.f+__expf(-rgbs[i*3+0]));
    float cg = 1.f/(1.f+__expf(-rgbs[i*3+1]));
    float cb = 1.f/(1.f+__expf(-rgbs[i*3+2]));

    const float4* t4 = (const float4*)s_tz;
    int rank = 0;
    #pragma unroll 4
    for (int jj = 0; jj < NGP4/4; ++jj) {
        float4 v = t4[jj];
        int j = 4*jj;
        rank += (v.x < tz) || (v.x == tz && (j+0) < i);
        rank += (v.y < tz) || (v.y == tz && (j+1) < i);
        rank += (v.z < tz) || (v.z == tz && (j+2) < i);
        rank += (v.w < tz) || (v.w == tz && (j+3) < i);
    }

    float4* row = (float4*)(params + rank*PR);
    row[0] = make_float4(mx, my, -hA, -Bc);
    row[1] = make_float4(-hC, K, cr, cg);
    row[2] = make_float4(cb, e, f, thr);
}

// Kernel 2: binning. One wave per 32x8 tile (4 waves/block). Ballot-compacts
// the depth-sorted rows surviving the exact box cull into tileParams[tile],
// preserving depth order (chunk-by-chunk ballot + prefix popcount).
__global__ __launch_bounds__(256) void gs_bin(
    const float* __restrict__ params, float* __restrict__ tileParams,
    int* __restrict__ tileCount)
{
    const int lane = threadIdx.x & 63;
    const int tile = blockIdx.x*4 + (threadIdx.x >> 6);
    const float xc = (float)((tile & 7)*32) + 16.0f;   // x half-span 15.5
    const float yc = (float)((tile >> 3)*8) + 4.0f;    // y half-span 3.5
    const float4* __restrict__ src = (const float4*)params;
    float4* __restrict__ dst = (float4*)(tileParams + (size_t)tile*MAXL*PR);
    int cnt = 0;
    for (int cch = 0; cch < NROWS/64; ++cch) {
        int idx = cch*64 + lane;
        float4 q0 = src[idx*3+0];
        float4 q1 = src[idx*3+1];
        float4 q2 = src[idx*3+2];
        float dymin = fmaxf(fabsf(yc - q0.y) - 3.5f, 0.f);
        float dxmin = fmaxf(fabsf(xc - q0.x) - 15.5f, 0.f);
        bool keep = !(fmaxf(q2.y*dymin*dymin, q2.z*dxmin*dxmin) > q2.w);
        unsigned long long bal = __ballot(keep);
        if (keep) {
            int pos = cnt + (int)__popcll(bal & ((1ull << lane) - 1ull));
            dst[pos*3+0] = q0; dst[pos*3+1] = q1; dst[pos*3+2] = q2;
        }
        cnt += (int)__popcll(bal);
    }
    if (lane == 0) tileCount[tile] = cnt;
}

// Kernel 3: compositing over the compacted list. grid = 1024 blocks:
// blockIdx = qtr*256 + tile (quarters of a hot tile land on different CUs).
// Block = 4 waves = 4 sub-segments of the tile's list quarter; thread = 4
// contiguous rows at one x (tile 32x8 = 64 lanes x 4 px). In-block LDS reduce
// of the 4 sub-segments -> one float4 (R,G,B,T) quarter-partial per pixel.
__global__ __launch_bounds__(256, 4) void gs_composite(
    const float* __restrict__ tileParams, const int* __restrict__ tileCount,
    float4* __restrict__ qpart)
{
    __shared__ float4 part[4][4][64];   // [row k][wave][tx]
    const int tx = threadIdx.x;
    const int wv = __builtin_amdgcn_readfirstlane((int)threadIdx.y);
    const int tile = blockIdx.x & 255;
    const int qtr  = blockIdx.x >> 8;
    const int x0 = (tile & 7)*32, y0 = (tile >> 3)*8;
    const float px = (float)(x0 + (tx & 31)) + 0.5f;
    const float yb = (float)(y0 + ((tx >> 5) << 2)) + 0.5f;

    const int L  = tileCount[tile];                // uniform (s_load)
    const int qc = (L + 3) >> 2;
    const int q0i = qtr*qc;
    const int qlen = min(qc, max(L - q0i, 0));
    const int wc = (qlen + 3) >> 2;
    const int c0 = q0i + wv*wc;
    const int c1 = min(c0 + wc, q0i + qlen);

    const float4* p = (const float4*)tileParams + (size_t)tile*(MAXL*3) + 3*c0;
    float T0=1.f,r0=0.f,g0=0.f,b0=0.f;
    float T1=1.f,r1=0.f,g1=0.f,b1=0.f;
    float T2=1.f,r2=0.f,g2=0.f,b2=0.f;
    float T3=1.f,r3=0.f,g3=0.f,b3=0.f;

    #pragma unroll 2
    for (int n = c0; n < c1; ++n, p += 3) {
        float4 a0 = p[0];                  // mx,my,A2n,B2n
        float4 a1 = p[1];                  // C2n,K,cr,cg
        float cb = p[2].x;
        float dx  = px - a0.x;
        float bdx = a0.w*dx;
        float axx = fmaf(a0.z*dx, dx, a1.y);    // A2n*dx^2 + K
        float dy0 = yb - a0.y;
        float dy1 = dy0 + 1.f, dy2 = dy0 + 2.f, dy3 = dy0 + 3.f;

        float sg0 = fmaf(bdx, dy0, fmaf(a1.x*dy0, dy0, axx));
        float al0 = __builtin_amdgcn_exp2f(sg0);
        al0 = (al0 < ALPHA_MIN_F) ? 0.f : al0;
        float w0 = T0*al0; r0 += w0*a1.z; g0 += w0*a1.w; b0 += w0*cb; T0 -= w0;

        float sg1 = fmaf(bdx, dy1, fmaf(a1.x*dy1, dy1, axx));
        float al1 = __builtin_amdgcn_exp2f(sg1);
        al1 = (al1 < ALPHA_MIN_F) ? 0.f : al1;
        float w1 = T1*al1; r1 += w1*a1.z; g1 += w1*a1.w; b1 += w1*cb; T1 -= w1;

        float sg2 = fmaf(bdx, dy2, fmaf(a1.x*dy2, dy2, axx));
        float al2 = __builtin_amdgcn_exp2f(sg2);
        al2 = (al2 < ALPHA_MIN_F) ? 0.f : al2;
        float w2 = T2*al2; r2 += w2*a1.z; g2 += w2*a1.w; b2 += w2*cb; T2 -= w2;

        float sg3 = fmaf(bdx, dy3, fmaf(a1.x*dy3, dy3, axx));
        float al3 = __builtin_amdgcn_exp2f(sg3);
        al3 = (al3 < ALPHA_MIN_F) ? 0.f : al3;
        float w3 = T3*al3; r3 += w3*a1.z; g3 += w3*a1.w; b3 += w3*cb; T3 -= w3;
    }

    part[0][wv][tx] = make_float4(r0,g0,b0,T0);
    part[1][wv][tx] = make_float4(r1,g1,b1,T1);
    part[2][wv][tx] = make_float4(r2,g2,b2,T2);
    part[3][wv][tx] = make_float4(r3,g3,b3,T3);
    __syncthreads();

    {   // wave wv reduces pixel-row wv of each thread's 4-row bundle
        const int k = wv;
        float R=0.f,G=0.f,B=0.f,T=1.f;
        #pragma unroll
        for (int s = 0; s < 4; ++s) {
            float4 v = part[k][s][tx];
            R += T*v.x; G += T*v.y; B += T*v.z; T *= v.w;
        }
        const int y = y0 + ((tx >> 5) << 2) + k;
        const int x = x0 + (tx & 31);
        qpart[qtr*NPX + y*WW + x] = make_float4(R,G,B,T);
    }
}

// Kernel 4: combine the 4 list-quarter partials in depth order.
__global__ __launch_bounds__(256) void gs_combine(
    const float4* __restrict__ qpart, float* __restrict__ out)
{
    const int px = blockIdx.x*256 + threadIdx.x;
    float4 p0 = qpart[px];
    float4 p1 = qpart[NPX + px];
    float4 p2 = qpart[2*NPX + px];
    float4 p3 = qpart[3*NPX + px];
    out[px*3+0] = p0.x + p0.w*(p1.x + p1.w*(p2.x + p2.w*p3.x));
    out[px*3+1] = p0.y + p0.w*(p1.y + p1.w*(p2.y + p2.w*p3.y));
    out[px*3+2] = p0.z + p0.w*(p1.z + p1.w*(p2.z + p2.w*p3.z));
}

extern "C" void kernel_launch(void* const* d_in, const int* in_sizes, int n_in,
                              void* d_out, int out_size, void* d_ws, size_t ws_size,
                              hipStream_t stream) {
    // d_in: 0=coords (unused by reference), 1=means, 2=quats, 3=scales, 4=opacities, 5=rgbs
    const float* means  = (const float*)d_in[1];
    const float* quats  = (const float*)d_in[2];
    const float* scales = (const float*)d_in[3];
    const float* opac   = (const float*)d_in[4];
    const float* rgbs   = (const float*)d_in[5];

    char* ws = (char*)d_ws;
    float* params     = (float*)(ws);                     // NROWS*PR floats = 36 KB
    int*   tileCount  = (int*)  (ws + (36<<10));          // 1 KB
    float* tileParams = (float*)(ws + (40<<10));          // 256*768*12*4 B = 9.4 MB
    float4* qpart     = (float4*)(ws + (10<<20));         // 4*65536*16 B = 4 MB

    gs_prep<<<3, 256, 0, stream>>>(means, quats, scales, opac, rgbs, params);
    gs_bin<<<64, 256, 0, stream>>>(params, tileParams, tileCount);
    gs_composite<<<1024, dim3(64,4), 0, stream>>>(tileParams, tileCount, qpart);
    gs_combine<<<NPX/256, 256, 0, stream>>>(qpart, (float*)d_out);
}